// Round 5
// baseline (311.313 us; speedup 1.0000x reference)
//
#include <hip/hip_runtime.h>

typedef float  f32x4 __attribute__((ext_vector_type(4)));
typedef short  s16x8 __attribute__((ext_vector_type(8)));
typedef short  s16x4 __attribute__((ext_vector_type(4)));
typedef unsigned short u16;

#define HDIM 1024
#define BATCH 32
#define SEQ 2048
#define NROWS (BATCH*SEQ)   // 65536

// k_score geometry: 256x256 tile, BK=64, 8 waves (2M x 4N), 512 threads, 1 blk/CU
#define NTILES 16           // K / 64
#define PLANE 4096          // elems per LDS plane: 128 rows x 32 (64B rows)

#define GLD16(gp, lp) __builtin_amdgcn_global_load_lds( \
    (const __attribute__((address_space(1))) void*)(gp), \
    (__attribute__((address_space(3))) void*)(lp), 16, 0, 0)

#define VMCNT(n) asm volatile("s_waitcnt vmcnt(" #n ")" ::: "memory")
#define BARRIER  asm volatile("s_barrier" ::: "memory")

__device__ __forceinline__ u16 f2bf(float f){
    unsigned u = __float_as_uint(f);
    u = u + 0x7FFFu + ((u >> 16) & 1u);   // RNE
    return (u16)(u >> 16);
}

__device__ __forceinline__ float tanh_fast(float x){
    float e = __builtin_amdgcn_exp2f(x * 2.885390082f);
    return 1.0f - 2.0f * __builtin_amdgcn_rcpf(e + 1.0f);
}

// ---------------- keys fp32 -> bf16, coalesced -----------------------------------
__global__ __launch_bounds__(256) void k_cvt(const float* __restrict__ in,
                                             u16* __restrict__ out){
    size_t base = (size_t)blockIdx.x * 256 + threadIdx.x;   // 524288 threads
    const f32x4* ip = (const f32x4*)in;
    s16x4* op = (s16x4*)out;
#pragma unroll 4
    for (int i = 0; i < 32; ++i){
        size_t c = base + (size_t)i * 524288;
        f32x4 v = ip[c];
        s16x4 o;
        o[0] = (short)f2bf(v.x); o[1] = (short)f2bf(v.y);
        o[2] = (short)f2bf(v.z); o[3] = (short)f2bf(v.w);
        op[c] = o;
    }
}

// ---------------- W1 -> W1T (bf16, transposed) -----------------------------------
__global__ __launch_bounds__(256) void k_w1t(const float* __restrict__ W1,
                                             u16* __restrict__ W1T){
    __shared__ u16 t[64][65];
    int blk = blockIdx.x;
    int bh = blk >> 4, bd = blk & 15;
    int h0 = bh * 64, d0 = bd * 64;
    int tid = threadIdx.x;
    int lh = tid >> 4, ld = (tid & 15) * 4;
#pragma unroll
    for (int i = 0; i < 4; ++i){
        int hh = lh + i * 16;
        f32x4 v = *(const f32x4*)&W1[(size_t)(h0 + hh) * HDIM + d0 + ld];
        t[hh][ld + 0] = f2bf(v.x);
        t[hh][ld + 1] = f2bf(v.y);
        t[hh][ld + 2] = f2bf(v.z);
        t[hh][ld + 3] = f2bf(v.w);
    }
    __syncthreads();
    int wv = tid >> 6, ln = tid & 63;
#pragma unroll
    for (int i = 0; i < 16; ++i){
        int d = i * 4 + wv;
        W1T[(size_t)(d0 + d) * HDIM + h0 + ln] = t[ln][d];
    }
}

// ---------------- qproj: 512 blocks, 4 h-quarter partials + LDS reduce -----------
__global__ __launch_bounds__(256) void k_qproj(const float* __restrict__ query,
                                               const float* __restrict__ W2,
                                               float* __restrict__ qproj){
    int b = blockIdx.x >> 4, dc = blockIdx.x & 15;
    int t = threadIdx.x;
    int dl = t & 63, hq = t >> 6;
    int d = dc * 64 + dl;
    const float* q = query + (size_t)b * HDIM;
    float acc = 0.f;
#pragma unroll 8
    for (int h = hq * 256; h < hq * 256 + 256; ++h)
        acc += q[h] * W2[(size_t)h * HDIM + d];
    __shared__ float red[4][64];
    red[hq][dl] = acc;
    __syncthreads();
    if (hq == 0)
        qproj[(size_t)b * HDIM + d] = red[0][dl] + red[1][dl] + red[2][dl] + red[3][dl];
}

// ---------------- 256^2 scores GEMM: counted-vmcnt, compiler-scheduled regions ---
// LDS planes: [buf(2)][half(2)][ks(2)] of 128 rows x 32 elems (64B rows).
// Swizzle (proven 0-conflict): LDS[r][slot] = G[r][slot ^ ((r>>1)&3)] per plane.
// Two barrier regions per K-tile (the hazard minimum). Each region:
//   {4 gload_lds stage || 12 ds_read_b128 || 32 MFMA}, compiler-interleaved.
// vmcnt: 4 loads issued/region, 8 in flight entering a region; VMCNT(4) waits
// exactly the half-tile about to be read. Never vmcnt(0) in-loop.
__global__ __launch_bounds__(512, 2) void k_score(const u16* __restrict__ keysbf,
                                                  const u16* __restrict__ W1T,
                                                  const float* __restrict__ qproj,
                                                  const float* __restrict__ V,
                                                  float* __restrict__ spart){
    int bid = blockIdx.x;
    int lid = (bid & 7) * 128 + (bid >> 3);   // XCD swizzle; 4 nt of one mt per XCD
    int mt  = lid >> 2;           // 0..255
    int nt  = lid & 3;            // 0..3

    __shared__ u16 As[8 * PLANE];   // 64 KB
    __shared__ u16 Bs[8 * PLANE];   // 64 KB

    int tid  = threadIdx.x;
    int lane = tid & 63, wave = tid >> 6;
    int wm = wave >> 2, wn = wave & 3;
    int g  = lane >> 4, q = lane & 15;

    // staging coords
    int sr = tid >> 2, sl = tid & 3;
    int ch = sl ^ ((sr >> 1) & 3);            // pre-swizzled global 16B chunk
    const u16* abase = keysbf + (size_t)(mt * 256 + sr) * HDIM + ch * 8;
    const u16* bbase = W1T    + (size_t)(nt * 256 + sr) * HDIM + ch * 8;
    int sdst = tid * 8;                       // lane*16B within plane

    auto stageA = [&](int buf, int t, int ks){
        int ko = t * 64 + ks * 32;
        GLD16(abase + ko,              &As[((buf << 2) | ks) * PLANE + sdst]);
        GLD16(abase + ko + 128 * HDIM, &As[((buf << 2) | 2 | ks) * PLANE + sdst]);
    };
    auto stageB = [&](int buf, int t, int ks){
        int ko = t * 64 + ks * 32;
        GLD16(bbase + ko,              &Bs[((buf << 2) | ks) * PLANE + sdst]);
        GLD16(bbase + ko + 128 * HDIM, &Bs[((buf << 2) | 2 | ks) * PLANE + sdst]);
    };

    // read offsets (swizzled, lane-constant across frags)
    int rslot = (g ^ ((q >> 1) & 3)) * 8;
    int arow  = q * 32 + rslot;                        // + m*512
    int brow  = ((wn & 1) * 64 + q) * 32 + rslot;      // + n*512

    f32x4 acc[8][4];
#pragma unroll
    for (int m = 0; m < 8; ++m)
#pragma unroll
        for (int n = 0; n < 4; ++n) acc[m][n] = 0.f;

    // prologue: tile 0, both halves (8 loads)
    stageA(0, 0, 0); stageB(0, 0, 0); stageA(0, 0, 1); stageB(0, 0, 1);

    for (int t = 0; t < NTILES; ++t){
        int c = t & 1, nb = c ^ 1;
        int tn = (t < NTILES - 1) ? t + 1 : NTILES - 1;   // dummy re-stage at tail
        s16x8 af[8], bq[4];
        const u16* Ap = &As[((c << 2) | (wm << 1)) * PLANE];
        const u16* Bp = &Bs[((c << 2) | ((wn >> 1) << 1)) * PLANE];

        // ---------- region 0: ks0 ----------
        VMCNT(4);                    // A,B ks0 of tile t landed (oldest 4 loads)
        BARRIER;
        stageA(nb, tn, 0);
        stageB(nb, tn, 0);
#pragma unroll
        for (int m = 0; m < 8; ++m) af[m] = *(const s16x8*)&Ap[arow + m * 512];
#pragma unroll
        for (int n = 0; n < 4; ++n) bq[n] = *(const s16x8*)&Bp[brow + n * 512];
        __builtin_amdgcn_s_setprio(1);
#pragma unroll
        for (int m = 0; m < 8; ++m)
#pragma unroll
            for (int n = 0; n < 4; ++n)
                acc[m][n] = __builtin_amdgcn_mfma_f32_16x16x32_bf16(af[m], bq[n], acc[m][n], 0, 0, 0);
        __builtin_amdgcn_s_setprio(0);

        // ---------- region 1: ks1 ----------
        Ap += PLANE; Bp += PLANE;
        VMCNT(4);                    // A,B ks1 of tile t landed
        BARRIER;
        stageA(nb, tn, 1);
        stageB(nb, tn, 1);
#pragma unroll
        for (int m = 0; m < 8; ++m) af[m] = *(const s16x8*)&Ap[arow + m * 512];
#pragma unroll
        for (int n = 0; n < 4; ++n) bq[n] = *(const s16x8*)&Bp[brow + n * 512];
        __builtin_amdgcn_s_setprio(1);
#pragma unroll
        for (int m = 0; m < 8; ++m)
#pragma unroll
            for (int n = 0; n < 4; ++n)
                acc[m][n] = __builtin_amdgcn_mfma_f32_16x16x32_bf16(af[m], bq[n], acc[m][n], 0, 0, 0);
        __builtin_amdgcn_s_setprio(0);
    }
    VMCNT(0);   // drain dummy stages before block retires (LDS dealloc safety)

    // ---- epilogue: spart[R][nt*4+wn] over this wave's 64 d-cols ----
    int b_idx = mt >> 3;                // 256 rows/tile, 2048/batch
    float Vn[4], Qn[4];
#pragma unroll
    for (int n = 0; n < 4; ++n){
        int D = nt * 256 + wn * 64 + n * 16 + q;
        Vn[n] = V[D];
        Qn[n] = qproj[(size_t)b_idx * HDIM + D];
    }
#pragma unroll
    for (int m = 0; m < 8; ++m){
#pragma unroll
        for (int r = 0; r < 4; ++r){
            float s = 0.f;
#pragma unroll
            for (int n = 0; n < 4; ++n){
                float x = acc[m][n][r] + Qn[n];
                s += Vn[n] * tanh_fast(x);
            }
            s += __shfl_xor(s, 1);
            s += __shfl_xor(s, 2);
            s += __shfl_xor(s, 4);
            s += __shfl_xor(s, 8);
            if (q == 0){
                int R = mt * 256 + wm * 128 + m * 16 + g * 4 + r;
                spart[(size_t)R * 16 + nt * 4 + wn] = s;
            }
        }
    }
}

// ---------------- softmax over S per batch ---------------------------------------
__global__ __launch_bounds__(256) void k_softmax(const float* __restrict__ spart,
                                                 const int* __restrict__ mask,
                                                 float* __restrict__ attn){
    int b = blockIdx.x;
    int tid = threadIdx.x;
    int lane = tid & 63, wv = tid >> 6;
    __shared__ float redmx[4];
    __shared__ float redsm[4];

    float sc[8];
#pragma unroll
    for (int i = 0; i < 8; ++i){
        int s = i * 256 + tid;
        const f32x4* p = (const f32x4*)&spart[(size_t)(b * SEQ + s) * 16];
        f32x4 v0 = p[0], v1 = p[1], v2 = p[2], v3 = p[3];
        float sum = (v0.x + v0.y + v0.z + v0.w) + (v1.x + v1.y + v1.z + v1.w)
                  + (v2.x + v2.y + v2.z + v2.w) + (v3.x + v3.y + v3.z + v3.w);
        sc[i] = (mask[b * SEQ + s] == 0) ? -1e9f : sum;
    }
    float mx = sc[0];
#pragma unroll
    for (int i = 1; i < 8; ++i) mx = fmaxf(mx, sc[i]);
#pragma unroll
    for (int o = 32; o >= 1; o >>= 1) mx = fmaxf(mx, __shfl_xor(mx, o));
    if (lane == 0) redmx[wv] = mx;
    __syncthreads();
    mx = fmaxf(fmaxf(redmx[0], redmx[1]), fmaxf(redmx[2], redmx[3]));

    float ex[8], ssum = 0.f;
#pragma unroll
    for (int i = 0; i < 8; ++i){
        ex[i] = __builtin_amdgcn_exp2f((sc[i] - mx) * 1.4426950408889634f);
        ssum += ex[i];
    }
#pragma unroll
    for (int o = 32; o >= 1; o >>= 1) ssum += __shfl_xor(ssum, o);
    if (lane == 0) redsm[wv] = ssum;
    __syncthreads();
    ssum = redsm[0] + redsm[1] + redsm[2] + redsm[3];
    float inv = 1.0f / ssum;
#pragma unroll
    for (int i = 0; i < 8; ++i)
        attn[(size_t)b * SEQ + i * 256 + tid] = ex[i] * inv;
}

// ---------------- context partials from bf16 keys: cpart[b][32][h] ---------------
__global__ __launch_bounds__(256) void k_ctxpart(const u16* __restrict__ keysbf,
                                                 const float* __restrict__ attn,
                                                 float* __restrict__ cpart){
    int blk = blockIdx.x;                 // 1024 blocks
    int b = blk >> 5, scn = blk & 31;     // 64 rows each
    int t = threadIdx.x;
    f32x4 acc = 0.f;
    const s16x4* kp = (const s16x4*)(keysbf + (size_t)(b * SEQ + scn * 64) * HDIM) + t;
    const float* ap = attn + (size_t)b * SEQ + scn * 64;
#pragma unroll 8
    for (int s = 0; s < 64; ++s){
        float a = ap[s];
        s16x4 kv = kp[(size_t)s * 256];
        f32x4 kf;
        kf.x = __uint_as_float((unsigned)(unsigned short)kv[0] << 16);
        kf.y = __uint_as_float((unsigned)(unsigned short)kv[1] << 16);
        kf.z = __uint_as_float((unsigned)(unsigned short)kv[2] << 16);
        kf.w = __uint_as_float((unsigned)(unsigned short)kv[3] << 16);
        acc += a * kf;
    }
    *(f32x4*)&cpart[(size_t)(b * 32 + scn) * HDIM + t * 4] = acc;
}

__global__ __launch_bounds__(256) void k_ctxred(const float* __restrict__ cpart,
                                                float* __restrict__ ctx){
    int idx = blockIdx.x * 256 + threadIdx.x;   // 128 blocks
    int b = idx >> 10, h = idx & 1023;
    float s = 0.f;
#pragma unroll
    for (int sc = 0; sc < 32; ++sc)
        s += cpart[(size_t)(b * 32 + sc) * HDIM + h];
    ctx[idx] = s;
}

// ---------------- launch ---------------------------------------------------------
extern "C" void kernel_launch(void* const* d_in, const int* in_sizes, int n_in,
                              void* d_out, int out_size, void* d_ws, size_t ws_size,
                              hipStream_t stream){
    (void)in_sizes; (void)n_in; (void)out_size; (void)ws_size;
    const float* query = (const float*)d_in[0];
    const float* keys  = (const float*)d_in[1];
    const int*   mask  = (const int*)d_in[2];
    const float* W1    = (const float*)d_in[3];
    const float* W2    = (const float*)d_in[4];
    const float* V     = (const float*)d_in[5];

    float* ctx_out  = (float*)d_out;            // [32][1024]
    float* attn_out = ctx_out + BATCH * HDIM;   // [32][2048]

    char* ws = (char*)d_ws;
    u16*   W1T   = (u16*)ws;                                   // 2 MB
    float* qproj = (float*)(ws + (2u << 20));                  // 128 KB
    float* spart = (float*)(ws + (2u << 20) + (128u << 10));   // 4 MB
    float* cpart = spart;   // ctxpart partials reuse spart (dead after softmax)
    u16*   keysbf= (u16*)(ws + (9u << 20));                    // 128 MB

    k_w1t    <<<dim3(256),  dim3(256), 0, stream>>>(W1, W1T);
    k_qproj  <<<dim3(512),  dim3(256), 0, stream>>>(query, W2, qproj);
    k_cvt    <<<dim3(2048), dim3(256), 0, stream>>>(keys, keysbf);
    k_score  <<<dim3(1024), dim3(512), 0, stream>>>(keysbf, W1T, qproj, V, spart);
    k_softmax<<<dim3(32),   dim3(256), 0, stream>>>(spart, mask, attn_out);
    k_ctxpart<<<dim3(1024), dim3(256), 0, stream>>>(keysbf, attn_out, cpart);
    k_ctxred <<<dim3(128),  dim3(256), 0, stream>>>(cpart, ctx_out);
}

// Round 6
// 296.923 us; speedup vs baseline: 1.0485x; 1.0485x over previous
//
#include <hip/hip_runtime.h>

typedef float  f32x4 __attribute__((ext_vector_type(4)));
typedef short  s16x8 __attribute__((ext_vector_type(8)));
typedef short  s16x4 __attribute__((ext_vector_type(4)));
typedef unsigned uint32x4 __attribute__((ext_vector_type(4)));
typedef unsigned short u16;

#define HDIM 1024
#define BATCH 32
#define SEQ 2048
#define NROWS (BATCH*SEQ)   // 65536

// k_score: 256x256 tile, BK=32, 8 waves (2M x 4N), 512 threads
#define BM 256
#define BN 256
#define BK 32
#define NKT (HDIM/BK)       // 32

#define GLD16(gp, lp) __builtin_amdgcn_global_load_lds( \
    (const __attribute__((address_space(1))) void*)(gp), \
    (__attribute__((address_space(3))) void*)(lp), 16, 0, 0)

#define VMCNT0  asm volatile("s_waitcnt vmcnt(0)" ::: "memory")
#define LGKM0   asm volatile("s_waitcnt lgkmcnt(0)" ::: "memory")
#define BARRIER asm volatile("s_barrier" ::: "memory")

__device__ __forceinline__ u16 f2bf(float f){
    unsigned u = __float_as_uint(f);
    u = u + 0x7FFFu + ((u >> 16) & 1u);   // RNE
    return (u16)(u >> 16);
}

__device__ __forceinline__ unsigned cvtpk(float lo, float hi){
    unsigned r;
    asm("v_cvt_pk_bf16_f32 %0, %1, %2" : "=v"(r) : "v"(lo), "v"(hi));
    return r;
}

__device__ __forceinline__ float tanh_fast(float x){
    float e = __builtin_amdgcn_exp2f(x * 2.885390082f);
    return 1.0f - 2.0f * __builtin_amdgcn_rcpf(e + 1.0f);
}

// ---------------- W1 -> W1T (bf16, transposed) -----------------------------------
__global__ __launch_bounds__(256) void k_w1t(const float* __restrict__ W1,
                                             u16* __restrict__ W1T){
    __shared__ u16 t[64][65];
    int blk = blockIdx.x;
    int bh = blk >> 4, bd = blk & 15;
    int h0 = bh * 64, d0 = bd * 64;
    int tid = threadIdx.x;
    int lh = tid >> 4, ld = (tid & 15) * 4;
#pragma unroll
    for (int i = 0; i < 4; ++i){
        int hh = lh + i * 16;
        f32x4 v = *(const f32x4*)&W1[(size_t)(h0 + hh) * HDIM + d0 + ld];
        t[hh][ld + 0] = f2bf(v.x);
        t[hh][ld + 1] = f2bf(v.y);
        t[hh][ld + 2] = f2bf(v.z);
        t[hh][ld + 3] = f2bf(v.w);
    }
    __syncthreads();
    int wv = tid >> 6, ln = tid & 63;
#pragma unroll
    for (int i = 0; i < 16; ++i){
        int d = i * 4 + wv;
        W1T[(size_t)(d0 + d) * HDIM + h0 + ln] = t[ln][d];
    }
}

// ---------------- qproj: 512 blocks, 4 h-quarter partials + LDS reduce -----------
__global__ __launch_bounds__(256) void k_qproj(const float* __restrict__ query,
                                               const float* __restrict__ W2,
                                               float* __restrict__ qproj){
    int b = blockIdx.x >> 4, dc = blockIdx.x & 15;
    int t = threadIdx.x;
    int dl = t & 63, hq = t >> 6;
    int d = dc * 64 + dl;
    const float* q = query + (size_t)b * HDIM;
    float acc = 0.f;
#pragma unroll 8
    for (int h = hq * 256; h < hq * 256 + 256; ++h)
        acc += q[h] * W2[(size_t)h * HDIM + d];
    __shared__ float red[4][64];
    red[hq][dl] = acc;
    __syncthreads();
    if (hq == 0)
        qproj[(size_t)b * HDIM + d] = red[0][dl] + red[1][dl] + red[2][dl] + red[3][dl];
}

// ---------------- fused cvt + scores GEMM ----------------------------------------
// A (keys, fp32) is reg-staged: global fp32 -> v_cvt_pk_bf16 -> swizzled ds_write.
// B (W1T, bf16) uses global_load_lds with pre-swizzled source.
// LDS layout (both A and B): LDS[r][slot] = G[r][slot ^ ((r>>1)&3)], rows 0..255
// of 32 bf16 (4 slots of 8). Proven 0-conflict on ds_read_b128 (round 3).
// ONE barrier per K-tile: writes into buf nb at tile t are ordered after all
// waves' reads of nb (tile t-1) by B1(t) alone; LGKM0 pins each wave's A-writes
// before it re-enters B1. VMCNT0 at tile top waits only B(t) (A already drained
// by the cvt's compiler wait vmcnt(4): A issued before B each tile => FIFO ok).
__global__ __launch_bounds__(512, 2) void k_score(const float* __restrict__ keys,
                                                  const u16* __restrict__ W1T,
                                                  const float* __restrict__ qproj,
                                                  const float* __restrict__ V,
                                                  float* __restrict__ spart){
    int bid = blockIdx.x;
    int lid = (bid & 7) * 128 + (bid >> 3);   // XCD swizzle; 4 nt of one mt per XCD
    int mt  = lid >> 2;           // 0..255
    int nt  = lid & 3;            // 0..3

    __shared__ u16 As[2][BM * BK];   // 16 KB per buf
    __shared__ u16 Bs[2][BM * BK];

    int tid  = threadIdx.x;
    int lane = tid & 63, wave = tid >> 6;
    int wm = wave >> 2, wn = wave & 3;
    int g  = lane >> 4, q = lane & 15;

    // ---- A reg-staging coords: thread t -> row ar (0..255), k-half ah ----
    int ar = tid >> 1, ah = tid & 1;
    const float* akey = keys + (size_t)(mt * BM + ar) * HDIM + ah * 16;
    int ax = (ar >> 1) & 3;                       // slot XOR for row ar
    int aw0 = ar * BK + ((2 * ah + 0) ^ ax) * 8;  // ds_write elem offsets
    int aw1 = ar * BK + ((2 * ah + 1) ^ ax) * 8;

    // ---- B staging (gload_lds, pre-swizzled source) ----
    int sr = tid >> 2, sl = tid & 3;
    int ch = sl ^ ((sr >> 1) & 3);
    const u16* bsrc = W1T + (size_t)(nt * BN + sr) * HDIM + ch * 8;
    int bdst = tid * 8;

    auto stageB = [&](int buf, int kt){
        int ko = kt * BK;
        GLD16(bsrc + ko,              &Bs[buf][bdst]);
        GLD16(bsrc + ko + 128 * HDIM, &Bs[buf][bdst + 128 * BK]);
    };

    // ---- read offsets (swizzled, lane-constant across frags) ----
    int rslot = (g ^ ((q >> 1) & 3)) * 8;
    int aoff = (wm * 128 + q) * BK + rslot;       // + m*16*BK per m-frag
    int boff = (wn * 64 + q) * BK + rslot;        // + n*16*BK per n-frag

    f32x4 acc[8][4];
#pragma unroll
    for (int m = 0; m < 8; ++m)
#pragma unroll
        for (int n = 0; n < 4; ++n) acc[m][n] = 0.f;

    // ---- prologue: stage tile 0 (A via regs, B via gload_lds) ----
    {
        f32x4 a0 = *(const f32x4*)(akey + 0);
        f32x4 a1 = *(const f32x4*)(akey + 4);
        f32x4 a2 = *(const f32x4*)(akey + 8);
        f32x4 a3 = *(const f32x4*)(akey + 12);
        stageB(0, 0);
        uint32x4 w0, w1;
        w0[0]=cvtpk(a0.x,a0.y); w0[1]=cvtpk(a0.z,a0.w);
        w0[2]=cvtpk(a1.x,a1.y); w0[3]=cvtpk(a1.z,a1.w);
        w1[0]=cvtpk(a2.x,a2.y); w1[1]=cvtpk(a2.z,a2.w);
        w1[2]=cvtpk(a3.x,a3.y); w1[3]=cvtpk(a3.z,a3.w);
        *(uint32x4*)&As[0][aw0] = w0;
        *(uint32x4*)&As[0][aw1] = w1;
        LGKM0;
    }

    for (int kt = 0; kt < NKT; ++kt){
        int c = kt & 1, nb = c ^ 1;
        int tn = (kt + 1 < NKT) ? kt + 1 : NKT - 1;   // dummy re-stage at tail

        VMCNT0;        // B(kt) landed (only B outstanding here)
        BARRIER;       // all waves: tile kt-1 reads done, tile kt stages visible

        // issue tile kt+1 staging loads (A first, then B: keeps FIFO so the
        // cvt's compiler wait is vmcnt(4) and B stays in flight)
        f32x4 a0 = *(const f32x4*)(akey + tn * BK + 0);
        f32x4 a1 = *(const f32x4*)(akey + tn * BK + 4);
        f32x4 a2 = *(const f32x4*)(akey + tn * BK + 8);
        f32x4 a3 = *(const f32x4*)(akey + tn * BK + 12);
        stageB(nb, tn);

        // compute tile kt
        s16x8 af[8], bq[4];
#pragma unroll
        for (int m = 0; m < 8; ++m) af[m] = *(const s16x8*)&As[c][aoff + m * 16 * BK];
#pragma unroll
        for (int n = 0; n < 4; ++n) bq[n] = *(const s16x8*)&Bs[c][boff + n * 512];
        __builtin_amdgcn_s_setprio(1);
#pragma unroll
        for (int m = 0; m < 8; ++m)
#pragma unroll
            for (int n = 0; n < 4; ++n)
                acc[m][n] = __builtin_amdgcn_mfma_f32_16x16x32_bf16(af[m], bq[n], acc[m][n], 0, 0, 0);
        __builtin_amdgcn_s_setprio(0);

        // finish staging kt+1: cvt (waits A loads, vmcnt(4)) + swizzled ds_write
        uint32x4 w0, w1;
        w0[0]=cvtpk(a0.x,a0.y); w0[1]=cvtpk(a0.z,a0.w);
        w0[2]=cvtpk(a1.x,a1.y); w0[3]=cvtpk(a1.z,a1.w);
        w1[0]=cvtpk(a2.x,a2.y); w1[1]=cvtpk(a2.z,a2.w);
        w1[2]=cvtpk(a3.x,a3.y); w1[3]=cvtpk(a3.z,a3.w);
        *(uint32x4*)&As[nb][aw0] = w0;
        *(uint32x4*)&As[nb][aw1] = w1;
        LGKM0;         // A-writes landed before this wave re-enters the barrier
    }
    VMCNT0;            // drain dummy B stage before LDS dealloc
    LGKM0;

    // ---- epilogue: spart[R][nt*4+wn] over this wave's 64 d-cols ----
    int b_idx = mt >> 3;
    float Vn[4], Qn[4];
#pragma unroll
    for (int n = 0; n < 4; ++n){
        int D = nt * BN + wn * 64 + n * 16 + q;
        Vn[n] = V[D];
        Qn[n] = qproj[(size_t)b_idx * HDIM + D];
    }
#pragma unroll
    for (int m = 0; m < 8; ++m){
#pragma unroll
        for (int r = 0; r < 4; ++r){
            float s = 0.f;
#pragma unroll
            for (int n = 0; n < 4; ++n){
                float x = acc[m][n][r] + Qn[n];
                s += Vn[n] * tanh_fast(x);
            }
            s += __shfl_xor(s, 1);
            s += __shfl_xor(s, 2);
            s += __shfl_xor(s, 4);
            s += __shfl_xor(s, 8);
            if (q == 0){
                int R = mt * BM + wm * 128 + m * 16 + g * 4 + r;
                spart[(size_t)R * 16 + nt * 4 + wn] = s;
            }
        }
    }
}

// ---------------- softmax over S per batch ---------------------------------------
__global__ __launch_bounds__(256) void k_softmax(const float* __restrict__ spart,
                                                 const int* __restrict__ mask,
                                                 float* __restrict__ attn){
    int b = blockIdx.x;
    int tid = threadIdx.x;
    int lane = tid & 63, wv = tid >> 6;
    __shared__ float redmx[4];
    __shared__ float redsm[4];

    float sc[8];
#pragma unroll
    for (int i = 0; i < 8; ++i){
        int s = i * 256 + tid;
        const f32x4* p = (const f32x4*)&spart[(size_t)(b * SEQ + s) * 16];
        f32x4 v0 = p[0], v1 = p[1], v2 = p[2], v3 = p[3];
        float sum = (v0.x + v0.y + v0.z + v0.w) + (v1.x + v1.y + v1.z + v1.w)
                  + (v2.x + v2.y + v2.z + v2.w) + (v3.x + v3.y + v3.z + v3.w);
        sc[i] = (mask[b * SEQ + s] == 0) ? -1e9f : sum;
    }
    float mx = sc[0];
#pragma unroll
    for (int i = 1; i < 8; ++i) mx = fmaxf(mx, sc[i]);
#pragma unroll
    for (int o = 32; o >= 1; o >>= 1) mx = fmaxf(mx, __shfl_xor(mx, o));
    if (lane == 0) redmx[wv] = mx;
    __syncthreads();
    mx = fmaxf(fmaxf(redmx[0], redmx[1]), fmaxf(redmx[2], redmx[3]));

    float ex[8], ssum = 0.f;
#pragma unroll
    for (int i = 0; i < 8; ++i){
        ex[i] = __builtin_amdgcn_exp2f((sc[i] - mx) * 1.4426950408889634f);
        ssum += ex[i];
    }
#pragma unroll
    for (int o = 32; o >= 1; o >>= 1) ssum += __shfl_xor(ssum, o);
    if (lane == 0) redsm[wv] = ssum;
    __syncthreads();
    ssum = redsm[0] + redsm[1] + redsm[2] + redsm[3];
    float inv = 1.0f / ssum;
#pragma unroll
    for (int i = 0; i < 8; ++i)
        attn[(size_t)b * SEQ + i * 256 + tid] = ex[i] * inv;
}

// ---------------- context partials (fp32 keys): cpart[b][32][h] ------------------
__global__ __launch_bounds__(256) void k_ctxpart(const float* __restrict__ keys,
                                                 const float* __restrict__ attn,
                                                 float* __restrict__ cpart){
    int blk = blockIdx.x;                 // 1024 blocks
    int b = blk >> 5, scn = blk & 31;     // 64 rows each
    int t = threadIdx.x;
    f32x4 acc = 0.f;
    const f32x4* kp = (const f32x4*)(keys + (size_t)(b * SEQ + scn * 64) * HDIM) + t;
    const float* ap = attn + (size_t)b * SEQ + scn * 64;
#pragma unroll 4
    for (int s = 0; s < 64; ++s){
        float a = ap[s];
        acc += a * kp[(size_t)s * 256];
    }
    *(f32x4*)&cpart[(size_t)(b * 32 + scn) * HDIM + t * 4] = acc;
}

__global__ __launch_bounds__(256) void k_ctxred(const float* __restrict__ cpart,
                                                float* __restrict__ ctx){
    int idx = blockIdx.x * 256 + threadIdx.x;   // 128 blocks
    int b = idx >> 10, h = idx & 1023;
    float s = 0.f;
#pragma unroll
    for (int sc = 0; sc < 32; ++sc)
        s += cpart[(size_t)(b * 32 + sc) * HDIM + h];
    ctx[idx] = s;
}

// ---------------- launch ---------------------------------------------------------
extern "C" void kernel_launch(void* const* d_in, const int* in_sizes, int n_in,
                              void* d_out, int out_size, void* d_ws, size_t ws_size,
                              hipStream_t stream){
    (void)in_sizes; (void)n_in; (void)out_size; (void)ws_size;
    const float* query = (const float*)d_in[0];
    const float* keys  = (const float*)d_in[1];
    const int*   mask  = (const int*)d_in[2];
    const float* W1    = (const float*)d_in[3];
    const float* W2    = (const float*)d_in[4];
    const float* V     = (const float*)d_in[5];

    float* ctx_out  = (float*)d_out;            // [32][1024]
    float* attn_out = ctx_out + BATCH * HDIM;   // [32][2048]

    char* ws = (char*)d_ws;
    u16*   W1T   = (u16*)ws;                                   // 2 MB
    float* qproj = (float*)(ws + (2u << 20));                  // 128 KB
    float* spart = (float*)(ws + (2u << 20) + (128u << 10));   // 4 MB
    float* cpart = spart;   // ctxpart partials reuse spart (dead after softmax)

    k_w1t    <<<dim3(256),  dim3(256), 0, stream>>>(W1, W1T);
    k_qproj  <<<dim3(512),  dim3(256), 0, stream>>>(query, W2, qproj);
    k_score  <<<dim3(1024), dim3(512), 0, stream>>>(keys, W1T, qproj, V, spart);
    k_softmax<<<dim3(32),   dim3(256), 0, stream>>>(spart, mask, attn_out);
    k_ctxpart<<<dim3(1024), dim3(256), 0, stream>>>(keys, attn_out, cpart);
    k_ctxred <<<dim3(128),  dim3(256), 0, stream>>>(cpart, ctx_out);
}